// Round 3
// baseline (79.908 us; speedup 1.0000x reference)
//
#include <hip/hip_runtime.h>
#include <hip/hip_bf16.h>
#include <stdint.h>
#include <math.h>

#define NN 8192
#define DD 128
#define NB 64                    // 8192/128 tiles per dim
#define NBLK (NB * (NB + 1) / 2) // 2080 upper-triangular blocks
#define NC 32                    // classes
#define NPB 32                   // class-sum partial blocks

typedef __attribute__((ext_vector_type(8))) short short8;
typedef __attribute__((ext_vector_type(4))) float f32x4;

__device__ __forceinline__ unsigned short f2bf_rne(float x) {
    union { float f; uint32_t u; } v; v.f = x;
    uint32_t r = v.u + 0x7FFFu + ((v.u >> 16) & 1u);
    return (unsigned short)(r >> 16);
}

// Fragment-major bf16 layout: byte = (row>>4)*4096 + (k>>3)*256 + (row&15)*16 + (k&7)*2
// -> an MFMA fragment (16 rows x 8 k) is one contiguous, coalesced 1KB wave-load.

// prep: blocks 0..511 cast 16 rows each into ybfA (= -2y) and ybfB (= y) frag-major,
// plus exact fp32 row norms. Blocks 512..543: per-class partial sums (32 blocks x 256 rows).
__global__ __launch_bounds__(256) void prep_kernel(const float* __restrict__ ys,
                                                   const int* __restrict__ lab,
                                                   unsigned short* __restrict__ ybfA,
                                                   unsigned short* __restrict__ ybfB,
                                                   float* __restrict__ sq,
                                                   float* __restrict__ clspart,
                                                   float* __restrict__ clscnt,
                                                   float* __restrict__ clssq,
                                                   float* __restrict__ negacc) {
    int b = blockIdx.x, t = threadIdx.x;
    __shared__ float cls[NC][DD];
    __shared__ float cnt[NC], csq[NC];
    if (b < 512) {
        int row = b * 16 + (t >> 4), c8 = t & 15;
        const float* base = ys + (size_t)row * DD + c8 * 8;
        float4 v0 = *(const float4*)base;
        float4 v1 = *(const float4*)(base + 4);
        uint32_t w0 = (uint32_t)f2bf_rne(v0.x) | ((uint32_t)f2bf_rne(v0.y) << 16);
        uint32_t w1 = (uint32_t)f2bf_rne(v0.z) | ((uint32_t)f2bf_rne(v0.w) << 16);
        uint32_t w2 = (uint32_t)f2bf_rne(v1.x) | ((uint32_t)f2bf_rne(v1.y) << 16);
        uint32_t w3 = (uint32_t)f2bf_rne(v1.z) | ((uint32_t)f2bf_rne(v1.w) << 16);
        uint4 outB = make_uint4(w0, w1, w2, w3);
        // -2*y exactly in bf16 bits: exp+1 (x2), flip sign. (exp never 255 for this data)
        uint4 outA = make_uint4((w0 + 0x00800080u) ^ 0x80008000u,
                                (w1 + 0x00800080u) ^ 0x80008000u,
                                (w2 + 0x00800080u) ^ 0x80008000u,
                                (w3 + 0x00800080u) ^ 0x80008000u);
        size_t off = (size_t)b * 4096 + c8 * 256 + (row & 15) * 16;
        *(uint4*)((char*)ybfB + off) = outB;
        *(uint4*)((char*)ybfA + off) = outA;
        float s = v0.x * v0.x + v0.y * v0.y + v0.z * v0.z + v0.w * v0.w
                + v1.x * v1.x + v1.y * v1.y + v1.z * v1.z + v1.w * v1.w;
        s += __shfl_xor(s, 1); s += __shfl_xor(s, 2);
        s += __shfl_xor(s, 4); s += __shfl_xor(s, 8);
        if (c8 == 0) sq[row] = s;
    } else {
        int pb = b - 512;
        for (int i = t; i < NC * DD; i += 256) ((float*)cls)[i] = 0.f;
        if (t < NC) { cnt[t] = 0.f; csq[t] = 0.f; }
        __syncthreads();
        int g = t >> 5, l32 = t & 31;
        for (int rr = g; rr < 256; rr += 8) {
            int row = pb * 256 + rr;
            int lb = lab[row];
            float4 v = *(const float4*)(ys + (size_t)row * DD + l32 * 4);
            atomicAdd(&cls[lb][l32 * 4 + 0], v.x);
            atomicAdd(&cls[lb][l32 * 4 + 1], v.y);
            atomicAdd(&cls[lb][l32 * 4 + 2], v.z);
            atomicAdd(&cls[lb][l32 * 4 + 3], v.w);
            float s = v.x * v.x + v.y * v.y + v.z * v.z + v.w * v.w;
            s += __shfl_xor(s, 1); s += __shfl_xor(s, 2);
            s += __shfl_xor(s, 4); s += __shfl_xor(s, 8); s += __shfl_xor(s, 16);
            if (l32 == 0) { atomicAdd(&cnt[lb], 1.f); atomicAdd(&csq[lb], s); }
        }
        __syncthreads();
        for (int i = t; i < NC * DD; i += 256) clspart[pb * NC * DD + i] = ((float*)cls)[i];
        if (t < NC) { clscnt[pb * NC + t] = cnt[t]; clssq[pb * NC + t] = csq[t]; }
        if (pb == 0 && t == 0) *negacc = 0.f;
    }
}

// loss: LDS-free, barrier-free tile GEMM. acc C-init = sq_i + sq_j; A = -2y,
// so acc ends as d2 directly. Epilogue: min-scan + wave-ballot; rare path only.
// Blocks 0..31 additionally reduce class partials -> analytic positive sums.
__global__ __launch_bounds__(256) void loss_kernel(const unsigned short* __restrict__ ybfA,
                                                   const unsigned short* __restrict__ ybfB,
                                                   const float* __restrict__ sq,
                                                   const int* __restrict__ lab,
                                                   const float* __restrict__ clspart,
                                                   const float* __restrict__ clscnt,
                                                   const float* __restrict__ clssq,
                                                   float* __restrict__ posval,
                                                   float* __restrict__ negacc) {
    int p = blockIdx.x, t = threadIdx.x;

    if (p < NC) {  // classred for class p: pos_c = n_c * sum_sq_c - ||S_c||^2
        __shared__ float sred[DD];
        __shared__ float aux[2];
        if (t < DD) {
            float S = 0.f;
            for (int pb = 0; pb < NPB; ++pb) S += clspart[pb * NC * DD + p * DD + t];
            sred[t] = S * S;
        } else if (t == 128) {
            float s = 0.f; for (int pb = 0; pb < NPB; ++pb) s += clscnt[pb * NC + p];
            aux[0] = s;
        } else if (t == 129) {
            float s = 0.f; for (int pb = 0; pb < NPB; ++pb) s += clssq[pb * NC + p];
            aux[1] = s;
        }
        __syncthreads();
        if (t == 0) {
            float ssq = 0.f;
            for (int d = 0; d < DD; ++d) ssq += sred[d];
            posval[p] = aux[0] * aux[1] - ssq;
        }
    }

    // Triangular decode: p -> (bi, bj), bi <= bj.
    int q = (NBLK - 1) - p;
    int r = (int)((sqrtf(8.0f * (float)q + 1.0f) - 1.0f) * 0.5f);
    while (r * (r + 1) / 2 > q) --r;
    while ((r + 1) * (r + 2) / 2 <= q) ++r;
    int bi = (NB - 1) - r;
    int bj = (NB - 1) - (q - r * (r + 1) / 2);
    int i0 = bi * 128, j0 = bj * 128;

    int wave = t >> 6, lane = t & 63;
    int wm = wave >> 1, wn = wave & 1;
    int lr = lane & 15, lg = lane >> 4;

    // Per-thread sq values (global loads, L1/L2-hot, broadcast-friendly).
    float sqa[4][4], sqb[4];
#pragma unroll
    for (int m = 0; m < 4; ++m)
#pragma unroll
        for (int qq = 0; qq < 4; ++qq) sqa[m][qq] = sq[i0 + wm * 64 + m * 16 + lg * 4 + qq];
#pragma unroll
    for (int n = 0; n < 4; ++n) sqb[n] = sq[j0 + wn * 64 + n * 16 + lr];

    f32x4 acc[4][4];
#pragma unroll
    for (int m = 0; m < 4; ++m)
#pragma unroll
        for (int n = 0; n < 4; ++n) {
            f32x4 a;
#pragma unroll
            for (int qq = 0; qq < 4; ++qq) a[qq] = sqa[m][qq] + sqb[n];
            acc[m][n] = a;
        }

    const char* pa = (const char*)ybfA + ((size_t)(i0 >> 4) + wm * 4) * 4096 + lg * 256 + lr * 16;
    const char* pbp = (const char*)ybfB + ((size_t)(j0 >> 4) + wn * 4) * 4096 + lg * 256 + lr * 16;

#pragma unroll
    for (int ks = 0; ks < 4; ++ks) {
        short8 af[4], bf[4];
#pragma unroll
        for (int m = 0; m < 4; ++m) af[m] = *(const short8*)(pa + m * 4096 + ks * 1024);
#pragma unroll
        for (int n = 0; n < 4; ++n) bf[n] = *(const short8*)(pbp + n * 4096 + ks * 1024);
#pragma unroll
        for (int m = 0; m < 4; ++m)
#pragma unroll
            for (int n = 0; n < 4; ++n)
                acc[m][n] = __builtin_amdgcn_mfma_f32_16x16x32_bf16(af[m], bf[n], acc[m][n], 0, 0, 0);
    }

    // acc[m][n][q] == d2(i,j). Negative term fires only if d2 < 1 (EPS^2=1): rare.
    float mn = acc[0][0][0];
#pragma unroll
    for (int m = 0; m < 4; ++m)
#pragma unroll
        for (int n = 0; n < 4; ++n)
#pragma unroll
            for (int qq = 0; qq < 4; ++qq) mn = fminf(mn, acc[m][n][qq]);

    if (__any(mn < 1.0f)) {
        float ns = 0.f;
#pragma unroll
        for (int m = 0; m < 4; ++m)
#pragma unroll
            for (int n = 0; n < 4; ++n)
#pragma unroll
                for (int qq = 0; qq < 4; ++qq) {
                    float d2 = acc[m][n][qq];
                    if (d2 < 1.0f) {
                        int i = i0 + wm * 64 + m * 16 + lg * 4 + qq;
                        int j = j0 + wn * 64 + n * 16 + lr;
                        if (i < j && lab[i] != lab[j]) {
                            float d = sqrtf(fmaxf(d2, 0.f));
                            float e = 1.0f - d;
                            ns += e * e;
                        }
                    }
                }
        if (ns != 0.f) atomicAdd(negacc, ns);
    }
}

__global__ __launch_bounds__(64) void finalize_kernel(const float* __restrict__ posval,
                                                      const float* __restrict__ negacc,
                                                      float* __restrict__ out) {
    int t = threadIdx.x;
    float s = (t < NC) ? posval[t] : 0.f;
#pragma unroll
    for (int off = 32; off >= 1; off >>= 1) s += __shfl_down(s, off);
    if (t == 0) out[0] = (s + negacc[0]) * (2.0f / ((float)NN * (float)(NN - 1)));
}

extern "C" void kernel_launch(void* const* d_in, const int* in_sizes, int n_in,
                              void* d_out, int out_size, void* d_ws, size_t ws_size,
                              hipStream_t stream) {
    const float* ys = (const float*)d_in[0];
    const int* lab = (const int*)d_in[1];
    float* out = (float*)d_out;

    char* w = (char*)d_ws;
    unsigned short* ybfA = (unsigned short*)(w);                       // 2 MB
    unsigned short* ybfB = (unsigned short*)(w + 2097152);             // 2 MB
    float* sq      = (float*)(w + 4194304);                            // 32 KB
    float* clspart = (float*)(w + 4227072);                            // 512 KB
    float* clscnt  = (float*)(w + 4751360);                            // 4 KB
    float* clssq   = (float*)(w + 4755456);                            // 4 KB
    float* posval  = (float*)(w + 4759552);                            // 128 B
    float* negacc  = (float*)(w + 4759680);                            // 4 B

    prep_kernel<<<544, 256, 0, stream>>>(ys, lab, ybfA, ybfB, sq, clspart, clscnt, clssq, negacc);
    loss_kernel<<<NBLK, 256, 0, stream>>>(ybfA, ybfB, sq, lab, clspart, clscnt, clssq, posval, negacc);
    finalize_kernel<<<1, 64, 0, stream>>>(posval, negacc, out);
}

// Round 4
// 40.843 us; speedup vs baseline: 1.9565x; 1.9565x over previous
//
#include <hip/hip_runtime.h>
#include <hip/hip_bf16.h>
#include <stdint.h>
#include <math.h>

#define NN 8192
#define DD 128
#define NB 64                    // 8192/128 tiles per dim
#define NBLK (NB * (NB + 1) / 2) // 2080 upper-triangular blocks
#define NC 32                    // classes
#define NPB 256                  // prep blocks (= class partial blocks)
#define RPB 32                   // rows per prep block

typedef __attribute__((ext_vector_type(8))) short short8;
typedef __attribute__((ext_vector_type(4))) float f32x4;

__device__ __forceinline__ unsigned short f2bf_rne(float x) {
    union { float f; uint32_t u; } v; v.f = x;
    uint32_t r = v.u + 0x7FFFu + ((v.u >> 16) & 1u);
    return (unsigned short)(r >> 16);
}

// Fragment-major bf16 layout: byte = (row>>4)*4096 + (k>>3)*256 + (row&15)*16 + (k&7)*2
// -> an MFMA fragment (16 rows x 8 k) is one contiguous, coalesced 1KB wave-load.

// prep: 256 blocks x 32 rows. Cast to ybfA (=-2y) / ybfB (=y) frag-major + exact
// fp32 row norms + per-block per-class partial sums (LDS, atomic-free: thread t
// exclusively owns column t of every class row).
__global__ __launch_bounds__(256) void prep_kernel(const float* __restrict__ ys,
                                                   const int* __restrict__ lab,
                                                   unsigned short* __restrict__ ybfA,
                                                   unsigned short* __restrict__ ybfB,
                                                   float* __restrict__ sq,
                                                   float* __restrict__ clspart,
                                                   float* __restrict__ negacc) {
    int b = blockIdx.x, t = threadIdx.x;
    __shared__ float cls[NC][DD];   // 16 KB
    __shared__ int slab[RPB];

    for (int i = t; i < NC * DD; i += 256) ((float*)cls)[i] = 0.f;
    if (t < RPB) slab[t] = lab[b * RPB + t];

#pragma unroll
    for (int u = 0; u < 2; ++u) {
        int rloc = (t >> 4) + u * 16;   // 0..31
        int c8 = t & 15;                // 16B chunk within row
        int row = b * RPB + rloc;
        const float* base = ys + (size_t)row * DD + c8 * 8;
        float4 v0 = *(const float4*)base;
        float4 v1 = *(const float4*)(base + 4);
        uint32_t w0 = (uint32_t)f2bf_rne(v0.x) | ((uint32_t)f2bf_rne(v0.y) << 16);
        uint32_t w1 = (uint32_t)f2bf_rne(v0.z) | ((uint32_t)f2bf_rne(v0.w) << 16);
        uint32_t w2 = (uint32_t)f2bf_rne(v1.x) | ((uint32_t)f2bf_rne(v1.y) << 16);
        uint32_t w3 = (uint32_t)f2bf_rne(v1.z) | ((uint32_t)f2bf_rne(v1.w) << 16);
        uint4 outB = make_uint4(w0, w1, w2, w3);
        // -2*y exactly in bf16 bits: exp+1 (x2), flip sign (no inf/nan in data).
        uint4 outA = make_uint4((w0 + 0x00800080u) ^ 0x80008000u,
                                (w1 + 0x00800080u) ^ 0x80008000u,
                                (w2 + 0x00800080u) ^ 0x80008000u,
                                (w3 + 0x00800080u) ^ 0x80008000u);
        size_t off = (size_t)(b * 2 + u) * 4096 + c8 * 256 + (row & 15) * 16;
        *(uint4*)((char*)ybfB + off) = outB;
        *(uint4*)((char*)ybfA + off) = outA;
        float s = v0.x * v0.x + v0.y * v0.y + v0.z * v0.z + v0.w * v0.w
                + v1.x * v1.x + v1.y * v1.y + v1.z * v1.z + v1.w * v1.w;
        s += __shfl_xor(s, 1); s += __shfl_xor(s, 2);
        s += __shfl_xor(s, 4); s += __shfl_xor(s, 8);
        if (c8 == 0) sq[row] = s;
    }
    __syncthreads();

    // Atomic-free class accumulation: serial over rows; only thread t writes
    // column t of any class row -> no races, no atomics.
    for (int rr = 0; rr < RPB; ++rr) {
        if (t < DD) {
            int lb = slab[rr];
            cls[lb][t] += ys[(size_t)(b * RPB + rr) * DD + t];
        }
    }
    __syncthreads();
    for (int i = t; i < NC * DD; i += 256) clspart[(size_t)b * NC * DD + i] = ((float*)cls)[i];
    if (b == 0 && t == 0) *negacc = 0.f;
}

// loss: LDS-free, barrier-free tile GEMM. acc C-init = sq_i + sq_j; A = -2y,
// so acc ends as d2 directly. Epilogue: min-scan; rare path only (EPS^2=1).
// Blocks 0..31 additionally reduce class partials -> analytic positive sums.
__global__ __launch_bounds__(256) void loss_kernel(const unsigned short* __restrict__ ybfA,
                                                   const unsigned short* __restrict__ ybfB,
                                                   const float* __restrict__ sq,
                                                   const int* __restrict__ lab,
                                                   const float* __restrict__ clspart,
                                                   float* __restrict__ posval,
                                                   float* __restrict__ negacc) {
    int p = blockIdx.x, t = threadIdx.x;

    if (p < NC) {  // classred for class p: pos_c = n_c * sum_sq_c - ||S_c||^2
        __shared__ float red[16];
        float S = 0.f;
        if (t < DD) {
            for (int pb = 0; pb < NPB; ++pb) S += clspart[(size_t)pb * NC * DD + p * DD + t];
        }
        float cnt = 0.f, ssq = 0.f;
        for (int rr = t; rr < NN; rr += 256) {
            if (lab[rr] == p) { cnt += 1.f; ssq += sq[rr]; }
        }
        float s2 = (t < DD) ? S * S : 0.f;
#pragma unroll
        for (int off = 32; off >= 1; off >>= 1) {
            cnt += __shfl_down(cnt, off);
            ssq += __shfl_down(ssq, off);
            s2  += __shfl_down(s2, off);
        }
        if ((t & 63) == 0) {
            int w = t >> 6;
            red[w] = cnt; red[4 + w] = ssq; red[8 + w] = s2;
        }
        __syncthreads();
        if (t == 0) {
            float c4 = red[0] + red[1] + red[2] + red[3];
            float q4 = red[4] + red[5] + red[6] + red[7];
            float s4 = red[8] + red[9] + red[10] + red[11];
            posval[p] = c4 * q4 - s4;
        }
    }

    // Triangular decode: p -> (bi, bj), bi <= bj.
    int q = (NBLK - 1) - p;
    int r = (int)((sqrtf(8.0f * (float)q + 1.0f) - 1.0f) * 0.5f);
    while (r * (r + 1) / 2 > q) --r;
    while ((r + 1) * (r + 2) / 2 <= q) ++r;
    int bi = (NB - 1) - r;
    int bj = (NB - 1) - (q - r * (r + 1) / 2);
    int i0 = bi * 128, j0 = bj * 128;

    int wave = t >> 6, lane = t & 63;
    int wm = wave >> 1, wn = wave & 1;
    int lr = lane & 15, lg = lane >> 4;

    float sqa[4][4], sqb[4];
#pragma unroll
    for (int m = 0; m < 4; ++m)
#pragma unroll
        for (int qq = 0; qq < 4; ++qq) sqa[m][qq] = sq[i0 + wm * 64 + m * 16 + lg * 4 + qq];
#pragma unroll
    for (int n = 0; n < 4; ++n) sqb[n] = sq[j0 + wn * 64 + n * 16 + lr];

    f32x4 acc[4][4];
#pragma unroll
    for (int m = 0; m < 4; ++m)
#pragma unroll
        for (int n = 0; n < 4; ++n) {
            f32x4 a;
#pragma unroll
            for (int qq = 0; qq < 4; ++qq) a[qq] = sqa[m][qq] + sqb[n];
            acc[m][n] = a;
        }

    const char* pa = (const char*)ybfA + ((size_t)(i0 >> 4) + wm * 4) * 4096 + lg * 256 + lr * 16;
    const char* pbp = (const char*)ybfB + ((size_t)(j0 >> 4) + wn * 4) * 4096 + lg * 256 + lr * 16;

#pragma unroll
    for (int ks = 0; ks < 4; ++ks) {
        short8 af[4], bf[4];
#pragma unroll
        for (int m = 0; m < 4; ++m) af[m] = *(const short8*)(pa + m * 4096 + ks * 1024);
#pragma unroll
        for (int n = 0; n < 4; ++n) bf[n] = *(const short8*)(pbp + n * 4096 + ks * 1024);
#pragma unroll
        for (int m = 0; m < 4; ++m)
#pragma unroll
            for (int n = 0; n < 4; ++n)
                acc[m][n] = __builtin_amdgcn_mfma_f32_16x16x32_bf16(af[m], bf[n], acc[m][n], 0, 0, 0);
    }

    // acc[m][n][q] == d2(i,j). Negative term fires only if d2 < 1: rare.
    float mn = acc[0][0][0];
#pragma unroll
    for (int m = 0; m < 4; ++m)
#pragma unroll
        for (int n = 0; n < 4; ++n)
#pragma unroll
            for (int qq = 0; qq < 4; ++qq) mn = fminf(mn, acc[m][n][qq]);

    if (__any(mn < 1.0f)) {
        float ns = 0.f;
#pragma unroll
        for (int m = 0; m < 4; ++m)
#pragma unroll
            for (int n = 0; n < 4; ++n)
#pragma unroll
                for (int qq = 0; qq < 4; ++qq) {
                    float d2 = acc[m][n][qq];
                    if (d2 < 1.0f) {
                        int i = i0 + wm * 64 + m * 16 + lg * 4 + qq;
                        int j = j0 + wn * 64 + n * 16 + lr;
                        if (i < j && lab[i] != lab[j]) {
                            float d = sqrtf(fmaxf(d2, 0.f));
                            float e = 1.0f - d;
                            ns += e * e;
                        }
                    }
                }
        if (ns != 0.f) atomicAdd(negacc, ns);
    }
}

__global__ __launch_bounds__(64) void finalize_kernel(const float* __restrict__ posval,
                                                      const float* __restrict__ negacc,
                                                      float* __restrict__ out) {
    int t = threadIdx.x;
    float s = (t < NC) ? posval[t] : 0.f;
#pragma unroll
    for (int off = 32; off >= 1; off >>= 1) s += __shfl_down(s, off);
    if (t == 0) out[0] = (s + negacc[0]) * (2.0f / ((float)NN * (float)(NN - 1)));
}

extern "C" void kernel_launch(void* const* d_in, const int* in_sizes, int n_in,
                              void* d_out, int out_size, void* d_ws, size_t ws_size,
                              hipStream_t stream) {
    const float* ys = (const float*)d_in[0];
    const int* lab = (const int*)d_in[1];
    float* out = (float*)d_out;

    char* w = (char*)d_ws;
    unsigned short* ybfA = (unsigned short*)(w);                  // 2 MB
    unsigned short* ybfB = (unsigned short*)(w + 2097152);        // 2 MB
    float* sq      = (float*)(w + 4194304);                       // 32 KB
    float* clspart = (float*)(w + 4227072);                       // 256*32*128*4 = 4 MB
    float* posval  = (float*)(w + 8421376);                       // 128 B
    float* negacc  = (float*)(w + 8421504);                       // 4 B

    prep_kernel<<<NPB, 256, 0, stream>>>(ys, lab, ybfA, ybfB, sq, clspart, negacc);
    loss_kernel<<<NBLK, 256, 0, stream>>>(ybfA, ybfB, sq, lab, clspart, posval, negacc);
    finalize_kernel<<<1, 64, 0, stream>>>(posval, negacc, out);
}

// Round 5
// 38.568 us; speedup vs baseline: 2.0719x; 1.0590x over previous
//
#include <hip/hip_runtime.h>
#include <hip/hip_bf16.h>
#include <stdint.h>
#include <math.h>

#define NN 8192
#define DD 128
#define NB 64                    // 8192/128 tiles per dim
#define NBLK (NB * (NB + 1) / 2) // 2080 upper-triangular blocks
#define NC 32                    // classes
#define NPB 256                  // prep blocks (= class partial blocks)
#define RPB 32                   // rows per prep block

typedef __attribute__((ext_vector_type(8))) short short8;
typedef __attribute__((ext_vector_type(4))) float f32x4;

__device__ __forceinline__ unsigned short f2bf_rne(float x) {
    union { float f; uint32_t u; } v; v.f = x;
    uint32_t r = v.u + 0x7FFFu + ((v.u >> 16) & 1u);
    return (unsigned short)(r >> 16);
}

// Fragment-major bf16 layout: byte = (row>>4)*4096 + (k>>3)*256 + (row&15)*16 + (k&7)*2
// -> an MFMA fragment (16 rows x 8 k) is one contiguous, coalesced 1KB wave-load.

// prep: 256 blocks x 32 rows. Cast to ybfA (=-2y) / ybfB (=y) frag-major + exact
// fp32 row norms + per-block per-class partial sums (2 LDS copies, atomic-free:
// thread group g x column col exclusively owns cls[g][*][col]).
__global__ __launch_bounds__(256) void prep_kernel(const float* __restrict__ ys,
                                                   const int* __restrict__ lab,
                                                   unsigned short* __restrict__ ybfA,
                                                   unsigned short* __restrict__ ybfB,
                                                   float* __restrict__ sq,
                                                   float* __restrict__ clspart,
                                                   float* __restrict__ negacc) {
    int b = blockIdx.x, t = threadIdx.x;
    __shared__ float cls[2][NC][DD];   // 32 KB
    __shared__ int slab[RPB];

#pragma unroll
    for (int i = 0; i < 8; ++i) ((float4*)cls)[i * 256 + t] = make_float4(0.f, 0.f, 0.f, 0.f);
    if (t < RPB) slab[t] = lab[b * RPB + t];

#pragma unroll
    for (int u = 0; u < 2; ++u) {
        int rloc = (t >> 4) + u * 16;   // 0..31
        int c8 = t & 15;                // 16B chunk within row
        int row = b * RPB + rloc;
        const float* base = ys + (size_t)row * DD + c8 * 8;
        float4 v0 = *(const float4*)base;
        float4 v1 = *(const float4*)(base + 4);
        uint32_t w0 = (uint32_t)f2bf_rne(v0.x) | ((uint32_t)f2bf_rne(v0.y) << 16);
        uint32_t w1 = (uint32_t)f2bf_rne(v0.z) | ((uint32_t)f2bf_rne(v0.w) << 16);
        uint32_t w2 = (uint32_t)f2bf_rne(v1.x) | ((uint32_t)f2bf_rne(v1.y) << 16);
        uint32_t w3 = (uint32_t)f2bf_rne(v1.z) | ((uint32_t)f2bf_rne(v1.w) << 16);
        uint4 outB = make_uint4(w0, w1, w2, w3);
        // -2*y exactly in bf16 bits: exp+1 (x2), flip sign (no inf/nan in data).
        uint4 outA = make_uint4((w0 + 0x00800080u) ^ 0x80008000u,
                                (w1 + 0x00800080u) ^ 0x80008000u,
                                (w2 + 0x00800080u) ^ 0x80008000u,
                                (w3 + 0x00800080u) ^ 0x80008000u);
        size_t off = (size_t)(b * 2 + u) * 4096 + c8 * 256 + (rloc & 15) * 16;
        *(uint4*)((char*)ybfB + off) = outB;
        *(uint4*)((char*)ybfA + off) = outA;
        float s = v0.x * v0.x + v0.y * v0.y + v0.z * v0.z + v0.w * v0.w
                + v1.x * v1.x + v1.y * v1.y + v1.z * v1.z + v1.w * v1.w;
        s += __shfl_xor(s, 1); s += __shfl_xor(s, 2);
        s += __shfl_xor(s, 4); s += __shfl_xor(s, 8);
        if (c8 == 0) sq[row] = s;
    }
    __syncthreads();

    // Atomic-free class accumulation: group g handles 16 rows into its own copy.
    {
        int g = t >> 7, col = t & 127;
#pragma unroll
        for (int rr = 0; rr < 16; ++rr) {
            int rloc = g * 16 + rr;
            cls[g][slab[rloc]][col] += ys[(size_t)(b * RPB + rloc) * DD + col];
        }
    }
    __syncthreads();
#pragma unroll
    for (int i = 0; i < 4; ++i) {
        float4 a = ((const float4*)cls[0])[i * 256 + t];
        float4 c = ((const float4*)cls[1])[i * 256 + t];
        ((float4*)(clspart + (size_t)b * NC * DD))[i * 256 + t] =
            make_float4(a.x + c.x, a.y + c.y, a.z + c.z, a.w + c.w);
    }
    if (b == 0 && t == 0) *negacc = 0.f;
}

// classred: block p (32 blocks x 1024 threads): pos_c = n_c * ssq_c - ||S_c||^2.
__global__ __launch_bounds__(1024) void classred_kernel(const float* __restrict__ clspart,
                                                        const int* __restrict__ lab,
                                                        const float* __restrict__ sq,
                                                        float* __restrict__ posval) {
    int p = blockIdx.x, t = threadIdx.x;
    int col = t & 127, qr = t >> 7;  // 8 pb-groups
    __shared__ float sp[8][DD];
    __shared__ float redc[16], reds[16], red2[2];

    float S = 0.f;
#pragma unroll 8
    for (int pb = qr; pb < NPB; pb += 8) S += clspart[(size_t)pb * NC * DD + p * DD + col];
    sp[qr][col] = S;

    float cnt = 0.f, ssq = 0.f;
#pragma unroll
    for (int rr = t; rr < NN; rr += 1024) {
        if (lab[rr] == p) { cnt += 1.f; ssq += sq[rr]; }
    }
#pragma unroll
    for (int off = 32; off >= 1; off >>= 1) {
        cnt += __shfl_down(cnt, off);
        ssq += __shfl_down(ssq, off);
    }
    if ((t & 63) == 0) { redc[t >> 6] = cnt; reds[t >> 6] = ssq; }
    __syncthreads();

    float s2 = 0.f;
    if (t < DD) {
        float Sc = 0.f;
#pragma unroll
        for (int q = 0; q < 8; ++q) Sc += sp[q][t];
        s2 = Sc * Sc;
    }
#pragma unroll
    for (int off = 32; off >= 1; off >>= 1) s2 += __shfl_down(s2, off);
    if (t < 128 && (t & 63) == 0) red2[t >> 6] = s2;
    __syncthreads();
    if (t == 0) {
        float c = 0.f, s = 0.f;
#pragma unroll
        for (int w = 0; w < 16; ++w) { c += redc[w]; s += reds[w]; }
        posval[p] = c * s - (red2[0] + red2[1]);
    }
}

// loss: LDS-free, barrier-free tile GEMM, register-double-buffered k-loop.
// acc C-init = sq_i + sq_j; A = -2y, so acc ends as d2 directly.
// Epilogue: min-scan; rare negative path only (EPS^2=1, d2 ~ 256).
__global__ __launch_bounds__(256) void loss_kernel(const unsigned short* __restrict__ ybfA,
                                                   const unsigned short* __restrict__ ybfB,
                                                   const float* __restrict__ sq,
                                                   const int* __restrict__ lab,
                                                   float* __restrict__ negacc) {
    int p = blockIdx.x, t = threadIdx.x;

    // Triangular decode: p -> (bi, bj), bi <= bj.
    int q = (NBLK - 1) - p;
    int r = (int)((sqrtf(8.0f * (float)q + 1.0f) - 1.0f) * 0.5f);
    while (r * (r + 1) / 2 > q) --r;
    while ((r + 1) * (r + 2) / 2 <= q) ++r;
    int bi = (NB - 1) - r;
    int bj = (NB - 1) - (q - r * (r + 1) / 2);
    int i0 = bi * 128, j0 = bj * 128;

    int wave = t >> 6, lane = t & 63;
    int wm = wave >> 1, wn = wave & 1;
    int lr = lane & 15, lg = lane >> 4;

    const char* pa = (const char*)ybfA + ((size_t)(i0 >> 4) + wm * 4) * 4096 + lg * 256 + lr * 16;
    const char* pbp = (const char*)ybfB + ((size_t)(j0 >> 4) + wn * 4) * 4096 + lg * 256 + lr * 16;

#define LDA(buf, ks) { _Pragma("unroll") for (int m = 0; m < 4; ++m) \
        buf[m] = *(const short8*)(pa + m * 4096 + (ks) * 1024); }
#define LDB(buf, ks) { _Pragma("unroll") for (int n = 0; n < 4; ++n) \
        buf[n] = *(const short8*)(pbp + n * 4096 + (ks) * 1024); }
#define STEP(abuf, bbuf) { _Pragma("unroll") for (int m = 0; m < 4; ++m) \
        { _Pragma("unroll") for (int n = 0; n < 4; ++n) \
            acc[m][n] = __builtin_amdgcn_mfma_f32_16x16x32_bf16(abuf[m], bbuf[n], acc[m][n], 0, 0, 0); } }

    short8 a0[4], b0[4], a1[4], b1[4];
    LDA(a0, 0) LDB(b0, 0)

    float sqa[4][4], sqb[4];
#pragma unroll
    for (int m = 0; m < 4; ++m)
#pragma unroll
        for (int qq = 0; qq < 4; ++qq) sqa[m][qq] = sq[i0 + wm * 64 + m * 16 + lg * 4 + qq];
#pragma unroll
    for (int n = 0; n < 4; ++n) sqb[n] = sq[j0 + wn * 64 + n * 16 + lr];

    f32x4 acc[4][4];
#pragma unroll
    for (int m = 0; m < 4; ++m)
#pragma unroll
        for (int n = 0; n < 4; ++n) {
            f32x4 a;
#pragma unroll
            for (int qq = 0; qq < 4; ++qq) a[qq] = sqa[m][qq] + sqb[n];
            acc[m][n] = a;
        }

    // Register-double-buffered pipeline: issue next step's loads before MFMAs.
    LDA(a1, 1) LDB(b1, 1)
    STEP(a0, b0)
    LDA(a0, 2) LDB(b0, 2)
    STEP(a1, b1)
    LDA(a1, 3) LDB(b1, 3)
    STEP(a0, b0)
    STEP(a1, b1)

    // acc[m][n][q] == d2(i,j). Negative term fires only if d2 < 1: rare.
    float mn = acc[0][0][0];
#pragma unroll
    for (int m = 0; m < 4; ++m)
#pragma unroll
        for (int n = 0; n < 4; ++n)
#pragma unroll
            for (int qq = 0; qq < 4; ++qq) mn = fminf(mn, acc[m][n][qq]);

    if (__any(mn < 1.0f)) {
        float ns = 0.f;
#pragma unroll
        for (int m = 0; m < 4; ++m)
#pragma unroll
            for (int n = 0; n < 4; ++n)
#pragma unroll
                for (int qq = 0; qq < 4; ++qq) {
                    float d2 = acc[m][n][qq];
                    if (d2 < 1.0f) {
                        int i = i0 + wm * 64 + m * 16 + lg * 4 + qq;
                        int j = j0 + wn * 64 + n * 16 + lr;
                        if (i < j && lab[i] != lab[j]) {
                            float d = sqrtf(fmaxf(d2, 0.f));
                            float e = 1.0f - d;
                            ns += e * e;
                        }
                    }
                }
        if (ns != 0.f) atomicAdd(negacc, ns);
    }
}

__global__ __launch_bounds__(64) void finalize_kernel(const float* __restrict__ posval,
                                                      const float* __restrict__ negacc,
                                                      float* __restrict__ out) {
    int t = threadIdx.x;
    float s = (t < NC) ? posval[t] : 0.f;
#pragma unroll
    for (int off = 32; off >= 1; off >>= 1) s += __shfl_down(s, off);
    if (t == 0) out[0] = (s + negacc[0]) * (2.0f / ((float)NN * (float)(NN - 1)));
}

extern "C" void kernel_launch(void* const* d_in, const int* in_sizes, int n_in,
                              void* d_out, int out_size, void* d_ws, size_t ws_size,
                              hipStream_t stream) {
    const float* ys = (const float*)d_in[0];
    const int* lab = (const int*)d_in[1];
    float* out = (float*)d_out;

    char* w = (char*)d_ws;
    unsigned short* ybfA = (unsigned short*)(w);                  // 2 MB
    unsigned short* ybfB = (unsigned short*)(w + 2097152);        // 2 MB
    float* sq      = (float*)(w + 4194304);                       // 32 KB
    float* clspart = (float*)(w + 4227072);                       // 256*32*128*4 = 4 MB
    float* posval  = (float*)(w + 8421376);                       // 128 B
    float* negacc  = (float*)(w + 8421504);                       // 4 B

    prep_kernel<<<NPB, 256, 0, stream>>>(ys, lab, ybfA, ybfB, sq, clspart, negacc);
    classred_kernel<<<NC, 1024, 0, stream>>>(clspart, lab, sq, posval);
    loss_kernel<<<NBLK, 256, 0, stream>>>(ybfA, ybfB, sq, lab, negacc);
    finalize_kernel<<<1, 64, 0, stream>>>(posval, negacc, out);
}